// Round 4
// baseline (366.333 us; speedup 1.0000x reference)
//
#include <hip/hip_runtime.h>

typedef _Float16 f16;
typedef _Float16 half4 __attribute__((ext_vector_type(4)));
typedef _Float16 half8 __attribute__((ext_vector_type(8)));
typedef float f32x4 __attribute__((ext_vector_type(4)));

#define RES 1024
#define NH 16
#define HD 64
#define BATCH 2
#define SEQ 2048
#define M_ROWS (BATCH * SEQ)

__device__ __forceinline__ void gload_lds16(const void* g, void* l) {
  __builtin_amdgcn_global_load_lds(
      (const __attribute__((address_space(1))) unsigned int*)g,
      (__attribute__((address_space(3))) unsigned int*)l, 16, 0, 0);
}

// ---------------- x: fp32 -> fp16 ----------------
__global__ __launch_bounds__(256) void xconv_kernel(const float* __restrict__ x,
                                                    f16* __restrict__ xh) {
  int idx = blockIdx.x * 256 + threadIdx.x;  // 8 floats per thread
  const float4* xv = (const float4*)x;
  float4 a = xv[idx * 2];
  float4 b = xv[idx * 2 + 1];
  half8 h;
  h[0] = (f16)a.x; h[1] = (f16)a.y; h[2] = (f16)a.z; h[3] = (f16)a.w;
  h[4] = (f16)b.x; h[5] = (f16)b.y; h[6] = (f16)b.z; h[7] = (f16)b.w;
  ((half8*)xh)[idx] = h;
}

// ---------------- W: fp32 [K,N] -> fp16 W^T [N,K] ----------------
__global__ __launch_bounds__(1024) void wtrans_kernel(const float* __restrict__ Wq,
                                                      const float* __restrict__ Wk,
                                                      const float* __restrict__ Wv,
                                                      f16* __restrict__ Wt) {
  const float* W = blockIdx.z == 0 ? Wq : (blockIdx.z == 1 ? Wk : Wv);
  f16* Wo = Wt + (size_t)blockIdx.z * RES * RES;
  __shared__ float tile[32][33];
  int n = blockIdx.x * 32 + threadIdx.x;
  int k = blockIdx.y * 32 + threadIdx.y;
  tile[threadIdx.y][threadIdx.x] = W[(size_t)k * RES + n];
  __syncthreads();
  int ko = blockIdx.y * 32 + threadIdx.x;
  int no = blockIdx.x * 32 + threadIdx.y;
  Wo[(size_t)no * RES + ko] = (f16)tile[threadIdx.x][threadIdx.y];
}

// ---------------- projections: C = x @ W  (B^T layout), m97-style ----------------
// writes Qh/Kh as [b,h,s,d], V transposed as Vt [b,h,d,s]
__global__ __launch_bounds__(256) void proj_gemm_kernel(const f16* __restrict__ xh,
                                                        const f16* __restrict__ Wt,
                                                        f16* __restrict__ Qh,
                                                        f16* __restrict__ Kh,
                                                        f16* __restrict__ Vt) {
  int proj = blockIdx.z;
  const f16* Bt = Wt + (size_t)proj * RES * RES;
  int m0 = blockIdx.x * 128;
  int n0 = blockIdx.y * 128;
  __shared__ alignas(16) f16 Als[128 * 32];
  __shared__ alignas(16) f16 Bls[128 * 32];
  int t = threadIdx.x, lane = t & 63, w = t >> 6;
  int l15 = lane & 15, quad = lane >> 4;
  int wm = w >> 1, wn = w & 1;

  f32x4 zero = {0.f, 0.f, 0.f, 0.f};
  f32x4 acc[4][4];
#pragma unroll
  for (int mt = 0; mt < 4; mt++)
#pragma unroll
    for (int nt = 0; nt < 4; nt++) acc[mt][nt] = zero;

  for (int k0 = 0; k0 < RES; k0 += 32) {
#pragma unroll
    for (int i = 0; i < 2; i++) {
      int wl = i * 256 + w * 64;   // wave-uniform linear base
      int linear = wl + lane;      // per-lane
      int row = linear >> 2;
      int kk = (linear & 3) * 8;
      gload_lds16(xh + (size_t)(m0 + row) * RES + k0 + kk, &Als[wl * 8]);
      gload_lds16(Bt + (size_t)(n0 + row) * RES + k0 + kk, &Bls[wl * 8]);
    }
    __syncthreads();
    half8 af[4], bf[4];
#pragma unroll
    for (int mt = 0; mt < 4; mt++)
      af[mt] = *(const half8*)&Als[(wm * 64 + mt * 16 + l15) * 32 + quad * 8];
#pragma unroll
    for (int nt = 0; nt < 4; nt++)
      bf[nt] = *(const half8*)&Bls[(wn * 64 + nt * 16 + l15) * 32 + quad * 8];
#pragma unroll
    for (int mt = 0; mt < 4; mt++)
#pragma unroll
      for (int nt = 0; nt < 4; nt++)
        acc[mt][nt] = __builtin_amdgcn_mfma_f32_16x16x32_f16(af[mt], bf[nt], acc[mt][nt], 0, 0, 0);
    __syncthreads();
  }

#pragma unroll
  for (int mt = 0; mt < 4; mt++) {
#pragma unroll
    for (int nt = 0; nt < 4; nt++) {
#pragma unroll
      for (int r = 0; r < 4; r++) {
        int row = m0 + wm * 64 + mt * 16 + quad * 4 + r;  // 0..4095
        int col = n0 + wn * 64 + nt * 16 + l15;           // 0..1023
        f16 v = (f16)acc[mt][nt][r];
        int b = row >> 11, s = row & (SEQ - 1);
        int h = col >> 6, d = col & (HD - 1);
        size_t bh = (size_t)b * NH + h;
        if (proj == 0)
          Qh[(bh * SEQ + s) * HD + d] = v;
        else if (proj == 1)
          Kh[(bh * SEQ + s) * HD + d] = v;
        else
          Vt[(bh * HD + d) * SEQ + s] = v;
      }
    }
  }
}

// ---------------- flash attention (v4) ----------------
// v4: 512-thread blocks, 8 waves; waves 0-3 / 4-7 split the KV range in half
// for the same 64 q-rows (fixed-m softmax partials add linearly), combined via
// LDS + one __syncthreads at the end. 32 waves/CU (vs 16), per-wave chain
// halved (16 kv iters). __launch_bounds__(512,8) caps VGPR at 64 so 8
// waves/SIMD materialize. XCD swizzle + S^T formulation kept from v3.
__global__ __launch_bounds__(512, 8) void flash_kernel(const f16* __restrict__ Qh,
                                                       const f16* __restrict__ Kh,
                                                       const f16* __restrict__ Vt,
                                                       float* __restrict__ out) {
  constexpr int PSTR = 72;  // halves; 144B row stride, 16B-aligned b128 reads
  constexpr int CSTR = 66;  // f32; 2-way banking on combine
  int L = blockIdx.x;
  int xcd = L & 7, slot = L >> 3;
  int bh = ((slot >> 5) << 3) | xcd;  // 32 qt-blocks of bh share one XCD
  int qt = slot & 31;
  int b = bh >> 4, h = bh & 15;
  int lane = threadIdx.x & 63, w = threadIdx.x >> 6;
  int qw = w & 3, half = w >> 2;
  int l15 = lane & 15, quad = lane >> 4;
  int qrow0 = qt * 64 + qw * 16;

  __shared__ alignas(16) f16 p_lds[8][16 * PSTR];
  __shared__ float comb_o[4][16 * CSTR];
  __shared__ float comb_l[4][16];

  // Q fragments (B-operand for S^T = K Q^T); fold in 1/sqrt(64)
  const f16* qptr = Qh + ((size_t)bh * SEQ + qrow0 + l15) * HD + quad * 8;
  half8 qf0 = *(const half8*)qptr;
  half8 qf1 = *(const half8*)(qptr + 32);
#pragma unroll
  for (int j = 0; j < 8; j++) { qf0[j] *= (f16)0.125f; qf1[j] *= (f16)0.125f; }

  f32x4 zero = {0.f, 0.f, 0.f, 0.f};
  float l_acc = 0.f;  // softmax denom for qrow = l15 (replicated across quads)
  f32x4 o[4];
#pragma unroll
  for (int i = 0; i < 4; i++) o[i] = zero;

  const f16* kbase = Kh + (size_t)bh * SEQ * HD;
  const f16* vbase = Vt + (size_t)bh * HD * SEQ;
  int kv_lo = half * (SEQ / 2);

  for (int i = 0; i < SEQ / 2; i += 64) {
    int kv0 = kv_lo + i;
    // ---- K loads (batched) ----
    half8 kf0[4], kf1[4];
#pragma unroll
    for (int tt = 0; tt < 4; tt++) {
      const f16* kp = kbase + (size_t)(kv0 + tt * 16 + l15) * HD + quad * 8;
      kf0[tt] = *(const half8*)kp;
      kf1[tt] = *(const half8*)(kp + 32);
    }
    // ---- S^T = K Q^T : C-layout col=qrow=l15, row=t=quad*4+r ----
    f32x4 sc[4];
#pragma unroll
    for (int tt = 0; tt < 4; tt++) {
      sc[tt] = __builtin_amdgcn_mfma_f32_16x16x32_f16(kf0[tt], qf0, zero, 0, 0, 0);
      sc[tt] = __builtin_amdgcn_mfma_f32_16x16x32_f16(kf1[tt], qf1, sc[tt], 0, 0, 0);
    }
    // ---- V loads issue now; latency covered by softmax + LDS below ----
    half8 vf0[4], vf1[4];
#pragma unroll
    for (int nt = 0; nt < 4; nt++) {
      const f16* vp = vbase + (size_t)(nt * 16 + l15) * SEQ + kv0 + quad * 8;
      vf0[nt] = *(const half8*)vp;
      vf1[nt] = *(const half8*)(vp + 32);
    }
    // ---- softmax (fixed m=0): P = exp(S); per-lane partial + 2 shuffles ----
    float ps = 0.f;
#pragma unroll
    for (int tt = 0; tt < 4; tt++)
#pragma unroll
      for (int r = 0; r < 4; r++) { sc[tt][r] = __expf(sc[tt][r]); ps += sc[tt][r]; }
    ps += __shfl_xor(ps, 16);
    ps += __shfl_xor(ps, 32);
    l_acc += ps;
    // ---- P^T -> LDS in A-layout rows: P[qrow=l15][t=tt*16+quad*4+r] ----
#pragma unroll
    for (int tt = 0; tt < 4; tt++) {
      half4 pk;
      pk[0] = (f16)sc[tt][0]; pk[1] = (f16)sc[tt][1];
      pk[2] = (f16)sc[tt][2]; pk[3] = (f16)sc[tt][3];
      *(half4*)&p_lds[w][l15 * PSTR + tt * 16 + quad * 4] = pk;
    }
    // ---- O += P V ----
#pragma unroll
    for (int ks = 0; ks < 2; ks++) {
      half8 pf = *(const half8*)&p_lds[w][l15 * PSTR + ks * 32 + quad * 8];
#pragma unroll
      for (int nt = 0; nt < 4; nt++)
        o[nt] = __builtin_amdgcn_mfma_f32_16x16x32_f16(pf, ks ? vf1[nt] : vf0[nt], o[nt], 0, 0, 0);
    }
  }

  // ---- cross-half combine: O = O0 + O1, l = l0 + l1 (exact with fixed m) ----
  if (half) {
#pragma unroll
    for (int nt = 0; nt < 4; nt++)
#pragma unroll
      for (int r = 0; r < 4; r++)
        comb_o[qw][(quad * 4 + r) * CSTR + nt * 16 + l15] = o[nt][r];
    if (quad == 0) comb_l[qw][l15] = l_acc;
  }
  __syncthreads();
  if (!half) {
    l_acc += comb_l[qw][l15];
    float linv[4];
#pragma unroll
    for (int r = 0; r < 4; r++) linv[r] = 1.0f / __shfl(l_acc, quad * 4 + r);
#pragma unroll
    for (int nt = 0; nt < 4; nt++) {
#pragma unroll
      for (int r = 0; r < 4; r++) {
        int s = qrow0 + quad * 4 + r;
        float v = o[nt][r] + comb_o[qw][(quad * 4 + r) * CSTR + nt * 16 + l15];
        out[((size_t)b * SEQ + s) * RES + h * HD + nt * 16 + l15] = v * linv[r];
      }
    }
  }
}

extern "C" void kernel_launch(void* const* d_in, const int* in_sizes, int n_in,
                              void* d_out, int out_size, void* d_ws, size_t ws_size,
                              hipStream_t stream) {
  (void)in_sizes; (void)n_in; (void)out_size; (void)ws_size;
  const float* x  = (const float*)d_in[0];
  const float* Wq = (const float*)d_in[1];
  const float* Wk = (const float*)d_in[2];
  const float* Wv = (const float*)d_in[3];
  float* out = (float*)d_out;

  // workspace layout (fp16): xh 8MB | Wt 6MB | Qh 8MB | Kh 8MB | Vt 8MB = 38MB
  f16* xh = (f16*)d_ws;
  f16* Wt = xh + (size_t)M_ROWS * RES;
  f16* Qh = Wt + (size_t)3 * RES * RES;
  f16* Kh = Qh + (size_t)BATCH * NH * SEQ * HD;
  f16* Vt = Kh + (size_t)BATCH * NH * SEQ * HD;

  xconv_kernel<<<M_ROWS * RES / (256 * 8), 256, 0, stream>>>(x, xh);
  wtrans_kernel<<<dim3(32, 32, 3), dim3(32, 32), 0, stream>>>(Wq, Wk, Wv, Wt);
  proj_gemm_kernel<<<dim3(M_ROWS / 128, RES / 128, 3), 256, 0, stream>>>(xh, Wt, Qh, Kh, Vt);
  flash_kernel<<<1024, 512, 0, stream>>>(Qh, Kh, Vt, out);
}

// Round 5
// 343.746 us; speedup vs baseline: 1.0657x; 1.0657x over previous
//
#include <hip/hip_runtime.h>

typedef _Float16 f16;
typedef _Float16 half4 __attribute__((ext_vector_type(4)));
typedef _Float16 half8 __attribute__((ext_vector_type(8)));
typedef float f32x4 __attribute__((ext_vector_type(4)));

#define RES 1024
#define NH 16
#define HD 64
#define BATCH 2
#define SEQ 2048
#define M_ROWS (BATCH * SEQ)

__device__ __forceinline__ void gload_lds16(const void* g, void* l) {
  __builtin_amdgcn_global_load_lds(
      (const __attribute__((address_space(1))) unsigned int*)g,
      (__attribute__((address_space(3))) unsigned int*)l, 16, 0, 0);
}

// ---------------- x: fp32 -> fp16 ----------------
__global__ __launch_bounds__(256) void xconv_kernel(const float* __restrict__ x,
                                                    f16* __restrict__ xh) {
  int idx = blockIdx.x * 256 + threadIdx.x;  // 8 floats per thread
  const float4* xv = (const float4*)x;
  float4 a = xv[idx * 2];
  float4 b = xv[idx * 2 + 1];
  half8 h;
  h[0] = (f16)a.x; h[1] = (f16)a.y; h[2] = (f16)a.z; h[3] = (f16)a.w;
  h[4] = (f16)b.x; h[5] = (f16)b.y; h[6] = (f16)b.z; h[7] = (f16)b.w;
  ((half8*)xh)[idx] = h;
}

// ---------------- W: fp32 [K,N] -> fp16 W^T [N,K] ----------------
__global__ __launch_bounds__(1024) void wtrans_kernel(const float* __restrict__ Wq,
                                                      const float* __restrict__ Wk,
                                                      const float* __restrict__ Wv,
                                                      f16* __restrict__ Wt) {
  const float* W = blockIdx.z == 0 ? Wq : (blockIdx.z == 1 ? Wk : Wv);
  f16* Wo = Wt + (size_t)blockIdx.z * RES * RES;
  __shared__ float tile[32][33];
  int n = blockIdx.x * 32 + threadIdx.x;
  int k = blockIdx.y * 32 + threadIdx.y;
  tile[threadIdx.y][threadIdx.x] = W[(size_t)k * RES + n];
  __syncthreads();
  int ko = blockIdx.y * 32 + threadIdx.x;
  int no = blockIdx.x * 32 + threadIdx.y;
  Wo[(size_t)no * RES + ko] = (f16)tile[threadIdx.x][threadIdx.y];
}

// ---------------- projections: C = x @ W  (B^T layout), m97-style ----------------
// writes Qh/Kh as [b,h,s,d], V transposed as Vt [b,h,d,s]
__global__ __launch_bounds__(256) void proj_gemm_kernel(const f16* __restrict__ xh,
                                                        const f16* __restrict__ Wt,
                                                        f16* __restrict__ Qh,
                                                        f16* __restrict__ Kh,
                                                        f16* __restrict__ Vt) {
  int proj = blockIdx.z;
  const f16* Bt = Wt + (size_t)proj * RES * RES;
  int m0 = blockIdx.x * 128;
  int n0 = blockIdx.y * 128;
  __shared__ alignas(16) f16 Als[128 * 32];
  __shared__ alignas(16) f16 Bls[128 * 32];
  int t = threadIdx.x, lane = t & 63, w = t >> 6;
  int l15 = lane & 15, quad = lane >> 4;
  int wm = w >> 1, wn = w & 1;

  f32x4 zero = {0.f, 0.f, 0.f, 0.f};
  f32x4 acc[4][4];
#pragma unroll
  for (int mt = 0; mt < 4; mt++)
#pragma unroll
    for (int nt = 0; nt < 4; nt++) acc[mt][nt] = zero;

  for (int k0 = 0; k0 < RES; k0 += 32) {
#pragma unroll
    for (int i = 0; i < 2; i++) {
      int wl = i * 256 + w * 64;   // wave-uniform linear base
      int linear = wl + lane;      // per-lane
      int row = linear >> 2;
      int kk = (linear & 3) * 8;
      gload_lds16(xh + (size_t)(m0 + row) * RES + k0 + kk, &Als[wl * 8]);
      gload_lds16(Bt + (size_t)(n0 + row) * RES + k0 + kk, &Bls[wl * 8]);
    }
    __syncthreads();
    half8 af[4], bf[4];
#pragma unroll
    for (int mt = 0; mt < 4; mt++)
      af[mt] = *(const half8*)&Als[(wm * 64 + mt * 16 + l15) * 32 + quad * 8];
#pragma unroll
    for (int nt = 0; nt < 4; nt++)
      bf[nt] = *(const half8*)&Bls[(wn * 64 + nt * 16 + l15) * 32 + quad * 8];
#pragma unroll
    for (int mt = 0; mt < 4; mt++)
#pragma unroll
      for (int nt = 0; nt < 4; nt++)
        acc[mt][nt] = __builtin_amdgcn_mfma_f32_16x16x32_f16(af[mt], bf[nt], acc[mt][nt], 0, 0, 0);
    __syncthreads();
  }

#pragma unroll
  for (int mt = 0; mt < 4; mt++) {
#pragma unroll
    for (int nt = 0; nt < 4; nt++) {
#pragma unroll
      for (int r = 0; r < 4; r++) {
        int row = m0 + wm * 64 + mt * 16 + quad * 4 + r;  // 0..4095
        int col = n0 + wn * 64 + nt * 16 + l15;           // 0..1023
        f16 v = (f16)acc[mt][nt][r];
        int b = row >> 11, s = row & (SEQ - 1);
        int h = col >> 6, d = col & (HD - 1);
        size_t bh = (size_t)b * NH + h;
        if (proj == 0)
          Qh[(bh * SEQ + s) * HD + d] = v;
        else if (proj == 1)
          Kh[(bh * SEQ + s) * HD + d] = v;
        else
          Vt[(bh * HD + d) * SEQ + s] = v;
      }
    }
  }
}

// ---------------- flash attention (v5) ----------------
// v5 = v3 body + __launch_bounds__(256,4) -> 128-VGPR budget. v3's VGPR=56
// left ~8 regs for load destinations: the 16 K/V loads per iter serialized
// into dependent L2 round-trips (~16x400cyc/iter) — THE plateau at ~240us.
// v4 proved occupancy isn't the limiter (86% occ, slower, spilled at VGPR=32).
// With 128 regs: 8 K loads batch (one exposed latency, overlapped across 4
// waves/SIMD); 8 V loads issue before softmax and hide behind exp+LDS.
// XCD swizzle + S^T formulation + fixed-m softmax kept.
__global__ __launch_bounds__(256, 4) void flash_kernel(const f16* __restrict__ Qh,
                                                       const f16* __restrict__ Kh,
                                                       const f16* __restrict__ Vt,
                                                       float* __restrict__ out) {
  constexpr int PSTR = 72;  // halves; 144B row stride, 16B-aligned b128 reads
  int L = blockIdx.x;
  int xcd = L & 7, slot = L >> 3;
  int bh = ((slot >> 5) << 3) | xcd;  // 32 qt-blocks of bh share one XCD
  int qt = slot & 31;
  int b = bh >> 4, h = bh & 15;
  int lane = threadIdx.x & 63, w = threadIdx.x >> 6;
  int l15 = lane & 15, quad = lane >> 4;
  int qrow0 = qt * 64 + w * 16;

  __shared__ alignas(16) f16 p_lds[4][16 * PSTR];

  // Q fragments (B-operand for S^T = K Q^T); fold in 1/sqrt(64)
  const f16* qptr = Qh + ((size_t)bh * SEQ + qrow0 + l15) * HD + quad * 8;
  half8 qf0 = *(const half8*)qptr;
  half8 qf1 = *(const half8*)(qptr + 32);
#pragma unroll
  for (int j = 0; j < 8; j++) { qf0[j] *= (f16)0.125f; qf1[j] *= (f16)0.125f; }

  f32x4 zero = {0.f, 0.f, 0.f, 0.f};
  float l_acc = 0.f;  // softmax denom for qrow = l15 (replicated across quads)
  f32x4 o[4];
#pragma unroll
  for (int i = 0; i < 4; i++) o[i] = zero;

  const f16* kbase = Kh + (size_t)bh * SEQ * HD;
  const f16* vbase = Vt + (size_t)bh * HD * SEQ;

  for (int kv0 = 0; kv0 < SEQ; kv0 += 64) {
    // ---- K loads (batched; 64 VGPRs of destinations, all in flight) ----
    half8 kf0[4], kf1[4];
#pragma unroll
    for (int tt = 0; tt < 4; tt++) {
      const f16* kp = kbase + (size_t)(kv0 + tt * 16 + l15) * HD + quad * 8;
      kf0[tt] = *(const half8*)kp;
      kf1[tt] = *(const half8*)(kp + 32);
    }
    // ---- S^T = K Q^T : C-layout col=qrow=l15, row=t=quad*4+r ----
    f32x4 sc[4];
#pragma unroll
    for (int tt = 0; tt < 4; tt++) {
      sc[tt] = __builtin_amdgcn_mfma_f32_16x16x32_f16(kf0[tt], qf0, zero, 0, 0, 0);
      sc[tt] = __builtin_amdgcn_mfma_f32_16x16x32_f16(kf1[tt], qf1, sc[tt], 0, 0, 0);
    }
    // ---- V loads issue now; latency covered by softmax + LDS below ----
    half8 vf0[4], vf1[4];
#pragma unroll
    for (int nt = 0; nt < 4; nt++) {
      const f16* vp = vbase + (size_t)(nt * 16 + l15) * SEQ + kv0 + quad * 8;
      vf0[nt] = *(const half8*)vp;
      vf1[nt] = *(const half8*)(vp + 32);
    }
    // ---- softmax (fixed m=0): P = exp(S); per-lane partial + 2 shuffles ----
    float ps = 0.f;
#pragma unroll
    for (int tt = 0; tt < 4; tt++)
#pragma unroll
      for (int r = 0; r < 4; r++) { sc[tt][r] = __expf(sc[tt][r]); ps += sc[tt][r]; }
    ps += __shfl_xor(ps, 16);
    ps += __shfl_xor(ps, 32);
    l_acc += ps;
    // ---- P^T -> LDS in A-layout rows: P[qrow=l15][t=tt*16+quad*4+r] ----
#pragma unroll
    for (int tt = 0; tt < 4; tt++) {
      half4 pk;
      pk[0] = (f16)sc[tt][0]; pk[1] = (f16)sc[tt][1];
      pk[2] = (f16)sc[tt][2]; pk[3] = (f16)sc[tt][3];
      *(half4*)&p_lds[w][l15 * PSTR + tt * 16 + quad * 4] = pk;
    }
    // ---- O += P V ----
#pragma unroll
    for (int ks = 0; ks < 2; ks++) {
      half8 pf = *(const half8*)&p_lds[w][l15 * PSTR + ks * 32 + quad * 8];
#pragma unroll
      for (int nt = 0; nt < 4; nt++)
        o[nt] = __builtin_amdgcn_mfma_f32_16x16x32_f16(pf, ks ? vf1[nt] : vf0[nt], o[nt], 0, 0, 0);
    }
  }

  // l for qrow = quad*4+r lives in lane with l15 = quad*4+r
  float linv[4];
#pragma unroll
  for (int r = 0; r < 4; r++) linv[r] = 1.0f / __shfl(l_acc, quad * 4 + r);
#pragma unroll
  for (int nt = 0; nt < 4; nt++) {
#pragma unroll
    for (int r = 0; r < 4; r++) {
      int s = qrow0 + quad * 4 + r;
      out[((size_t)b * SEQ + s) * RES + h * HD + nt * 16 + l15] = o[nt][r] * linv[r];
    }
  }
}

extern "C" void kernel_launch(void* const* d_in, const int* in_sizes, int n_in,
                              void* d_out, int out_size, void* d_ws, size_t ws_size,
                              hipStream_t stream) {
  (void)in_sizes; (void)n_in; (void)out_size; (void)ws_size;
  const float* x  = (const float*)d_in[0];
  const float* Wq = (const float*)d_in[1];
  const float* Wk = (const float*)d_in[2];
  const float* Wv = (const float*)d_in[3];
  float* out = (float*)d_out;

  // workspace layout (fp16): xh 8MB | Wt 6MB | Qh 8MB | Kh 8MB | Vt 8MB = 38MB
  f16* xh = (f16*)d_ws;
  f16* Wt = xh + (size_t)M_ROWS * RES;
  f16* Qh = Wt + (size_t)3 * RES * RES;
  f16* Kh = Qh + (size_t)BATCH * NH * SEQ * HD;
  f16* Vt = Kh + (size_t)BATCH * NH * SEQ * HD;

  xconv_kernel<<<M_ROWS * RES / (256 * 8), 256, 0, stream>>>(x, xh);
  wtrans_kernel<<<dim3(32, 32, 3), dim3(32, 32), 0, stream>>>(Wq, Wk, Wv, Wt);
  proj_gemm_kernel<<<dim3(M_ROWS / 128, RES / 128, 3), 256, 0, stream>>>(xh, Wt, Qh, Kh, Vt);
  flash_kernel<<<1024, 256, 0, stream>>>(Qh, Kh, Vt, out);
}

// Round 6
// 179.727 us; speedup vs baseline: 2.0383x; 1.9126x over previous
//
#include <hip/hip_runtime.h>

typedef _Float16 f16;
typedef _Float16 half4 __attribute__((ext_vector_type(4)));
typedef _Float16 half8 __attribute__((ext_vector_type(8)));
typedef float f32x4 __attribute__((ext_vector_type(4)));

#define RES 1024
#define NH 16
#define HD 64
#define BATCH 2
#define SEQ 2048
#define M_ROWS (BATCH * SEQ)

__device__ __forceinline__ void gload_lds16(const void* g, void* l) {
  __builtin_amdgcn_global_load_lds(
      (const __attribute__((address_space(1))) unsigned int*)g,
      (__attribute__((address_space(3))) unsigned int*)l, 16, 0, 0);
}

// ---------------- x: fp32 -> fp16 ----------------
__global__ __launch_bounds__(256) void xconv_kernel(const float* __restrict__ x,
                                                    f16* __restrict__ xh) {
  int idx = blockIdx.x * 256 + threadIdx.x;  // 8 floats per thread
  const float4* xv = (const float4*)x;
  float4 a = xv[idx * 2];
  float4 b = xv[idx * 2 + 1];
  half8 h;
  h[0] = (f16)a.x; h[1] = (f16)a.y; h[2] = (f16)a.z; h[3] = (f16)a.w;
  h[4] = (f16)b.x; h[5] = (f16)b.y; h[6] = (f16)b.z; h[7] = (f16)b.w;
  ((half8*)xh)[idx] = h;
}

// ---------------- W: fp32 [K,N] -> fp16 W^T [N,K] ----------------
__global__ __launch_bounds__(1024) void wtrans_kernel(const float* __restrict__ Wq,
                                                      const float* __restrict__ Wk,
                                                      const float* __restrict__ Wv,
                                                      f16* __restrict__ Wt) {
  const float* W = blockIdx.z == 0 ? Wq : (blockIdx.z == 1 ? Wk : Wv);
  f16* Wo = Wt + (size_t)blockIdx.z * RES * RES;
  __shared__ float tile[32][33];
  int n = blockIdx.x * 32 + threadIdx.x;
  int k = blockIdx.y * 32 + threadIdx.y;
  tile[threadIdx.y][threadIdx.x] = W[(size_t)k * RES + n];
  __syncthreads();
  int ko = blockIdx.y * 32 + threadIdx.x;
  int no = blockIdx.x * 32 + threadIdx.y;
  Wo[(size_t)no * RES + ko] = (f16)tile[threadIdx.x][threadIdx.y];
}

// ---------------- projections: C = x @ W  (B^T layout), m97-style ----------------
// writes Qh/Kh as [b,h,s,d], V transposed as Vt [b,h,d,s]
__global__ __launch_bounds__(256) void proj_gemm_kernel(const f16* __restrict__ xh,
                                                        const f16* __restrict__ Wt,
                                                        f16* __restrict__ Qh,
                                                        f16* __restrict__ Kh,
                                                        f16* __restrict__ Vt) {
  int proj = blockIdx.z;
  const f16* Bt = Wt + (size_t)proj * RES * RES;
  int m0 = blockIdx.x * 128;
  int n0 = blockIdx.y * 128;
  __shared__ alignas(16) f16 Als[128 * 32];
  __shared__ alignas(16) f16 Bls[128 * 32];
  int t = threadIdx.x, lane = t & 63, w = t >> 6;
  int l15 = lane & 15, quad = lane >> 4;
  int wm = w >> 1, wn = w & 1;

  f32x4 zero = {0.f, 0.f, 0.f, 0.f};
  f32x4 acc[4][4];
#pragma unroll
  for (int mt = 0; mt < 4; mt++)
#pragma unroll
    for (int nt = 0; nt < 4; nt++) acc[mt][nt] = zero;

  for (int k0 = 0; k0 < RES; k0 += 32) {
#pragma unroll
    for (int i = 0; i < 2; i++) {
      int wl = i * 256 + w * 64;   // wave-uniform linear base
      int linear = wl + lane;      // per-lane
      int row = linear >> 2;
      int kk = (linear & 3) * 8;
      gload_lds16(xh + (size_t)(m0 + row) * RES + k0 + kk, &Als[wl * 8]);
      gload_lds16(Bt + (size_t)(n0 + row) * RES + k0 + kk, &Bls[wl * 8]);
    }
    __syncthreads();
    half8 af[4], bf[4];
#pragma unroll
    for (int mt = 0; mt < 4; mt++)
      af[mt] = *(const half8*)&Als[(wm * 64 + mt * 16 + l15) * 32 + quad * 8];
#pragma unroll
    for (int nt = 0; nt < 4; nt++)
      bf[nt] = *(const half8*)&Bls[(wn * 64 + nt * 16 + l15) * 32 + quad * 8];
#pragma unroll
    for (int mt = 0; mt < 4; mt++)
#pragma unroll
      for (int nt = 0; nt < 4; nt++)
        acc[mt][nt] = __builtin_amdgcn_mfma_f32_16x16x32_f16(af[mt], bf[nt], acc[mt][nt], 0, 0, 0);
    __syncthreads();
  }

#pragma unroll
  for (int mt = 0; mt < 4; mt++) {
#pragma unroll
    for (int nt = 0; nt < 4; nt++) {
#pragma unroll
      for (int r = 0; r < 4; r++) {
        int row = m0 + wm * 64 + mt * 16 + quad * 4 + r;  // 0..4095
        int col = n0 + wn * 64 + nt * 16 + l15;           // 0..1023
        f16 v = (f16)acc[mt][nt][r];
        int b = row >> 11, s = row & (SEQ - 1);
        int h = col >> 6, d = col & (HD - 1);
        size_t bh = (size_t)b * NH + h;
        if (proj == 0)
          Qh[(bh * SEQ + s) * HD + d] = v;
        else if (proj == 1)
          Kh[(bh * SEQ + s) * HD + d] = v;
        else
          Vt[(bh * HD + d) * SEQ + s] = v;
      }
    }
  }
}

// ---------------- flash attention (v6) ----------------
// v6: K/V staged ONCE per block per iter via global_load_lds (v2-v5 had every
// wave re-loading the same K/V tiles from global: 4x redundant L1/line traffic,
// 16-line-divergent loads — the invariant behind the 240us plateau).
// XOR chunk swizzle (phys = log ^ (row&7)) applied on the GLOBAL address at
// staging (LDS dest must stay lane-linear per m104/m108) and on the LDS
// address at read: stride-128B fragment reads become bank-conflict-free.
// XCD swizzle + S^T formulation + fixed-m softmax + per-wave p_lds kept.
__global__ __launch_bounds__(256, 4) void flash_kernel(const f16* __restrict__ Qh,
                                                       const f16* __restrict__ Kh,
                                                       const f16* __restrict__ Vt,
                                                       float* __restrict__ out) {
  constexpr int PSTR = 72;  // halves; 144B row stride, 16B-aligned b128 reads
  int L = blockIdx.x;
  int xcd = L & 7, slot = L >> 3;
  int bh = ((slot >> 5) << 3) | xcd;  // 32 qt-blocks of bh share one XCD
  int qt = slot & 31;
  int b = bh >> 4, h = bh & 15;
  int tid = threadIdx.x;
  int lane = tid & 63, w = tid >> 6;
  int l15 = lane & 15, quad = lane >> 4;
  int qrow0 = qt * 64 + w * 16;

  __shared__ alignas(16) f16 Kls[64 * 64];  // [t_local][d], 16B chunks XOR-swizzled by row&7
  __shared__ alignas(16) f16 Vls[64 * 64];  // [d][t_local], same swizzle
  __shared__ alignas(16) f16 p_lds[4][16 * PSTR];

  // staging map: thread covers (row = tid>>3, chunk slot = tid&3..7)
  int srow_lo = tid >> 3;   // 0..31 (round adds +32)
  int schunk = tid & 7;

  // Q fragments (B-operand for S^T = K Q^T); fold in 1/sqrt(64)
  const f16* qptr = Qh + ((size_t)bh * SEQ + qrow0 + l15) * HD + quad * 8;
  half8 qf0 = *(const half8*)qptr;
  half8 qf1 = *(const half8*)(qptr + 32);
#pragma unroll
  for (int j = 0; j < 8; j++) { qf0[j] *= (f16)0.125f; qf1[j] *= (f16)0.125f; }

  f32x4 zero = {0.f, 0.f, 0.f, 0.f};
  float l_acc = 0.f;  // softmax denom for qrow = l15 (replicated across quads)
  f32x4 o[4];
#pragma unroll
  for (int i = 0; i < 4; i++) o[i] = zero;

  const f16* kbase = Kh + (size_t)bh * SEQ * HD;
  const f16* vbase = Vt + (size_t)bh * HD * SEQ;

  // swizzled LDS read offsets (halves): row*64 + (chunk ^ (row&7))*8
  int swz0 = (quad ^ (l15 & 7)) * 8;        // log chunks 0..3
  int swz1 = ((quad + 4) ^ (l15 & 7)) * 8;  // log chunks 4..7

  for (int kv0 = 0; kv0 < SEQ; kv0 += 64) {
    // ---- cooperative staging: K tile (64t x 64d) + V tile (64d x 64t) ----
#pragma unroll
    for (int round = 0; round < 2; round++) {
      int row = round * 32 + srow_lo;
      int pc = schunk ^ (row & 7);
      // K: rows are t (contiguous 128B in Kh)
      gload_lds16(kbase + ((size_t)(kv0 + row) << 6) + pc * 8,
                  &Kls[round * 2048 + w * 512]);
      // V: rows are d (stride SEQ halves in Vt)
      gload_lds16(vbase + ((size_t)row * SEQ) + kv0 + pc * 8,
                  &Vls[round * 2048 + w * 512]);
    }
    __syncthreads();  // drains vmcnt: staging complete

    // ---- K fragments from LDS ----
    half8 kf0[4], kf1[4];
#pragma unroll
    for (int tt = 0; tt < 4; tt++) {
      int row = tt * 16 + l15;
      kf0[tt] = *(const half8*)&Kls[row * 64 + swz0];
      kf1[tt] = *(const half8*)&Kls[row * 64 + swz1];
    }
    // ---- S^T = K Q^T : C-layout col=qrow=l15, row=t=quad*4+r ----
    f32x4 sc[4];
#pragma unroll
    for (int tt = 0; tt < 4; tt++) {
      sc[tt] = __builtin_amdgcn_mfma_f32_16x16x32_f16(kf0[tt], qf0, zero, 0, 0, 0);
      sc[tt] = __builtin_amdgcn_mfma_f32_16x16x32_f16(kf1[tt], qf1, sc[tt], 0, 0, 0);
    }
    // ---- V fragments from LDS ----
    half8 vf0[4], vf1[4];
#pragma unroll
    for (int nt = 0; nt < 4; nt++) {
      int row = nt * 16 + l15;
      vf0[nt] = *(const half8*)&Vls[row * 64 + swz0];
      vf1[nt] = *(const half8*)&Vls[row * 64 + swz1];
    }
    // ---- softmax (fixed m=0): P = exp(S); per-lane partial + 2 shuffles ----
    float ps = 0.f;
#pragma unroll
    for (int tt = 0; tt < 4; tt++)
#pragma unroll
      for (int r = 0; r < 4; r++) { sc[tt][r] = __expf(sc[tt][r]); ps += sc[tt][r]; }
    ps += __shfl_xor(ps, 16);
    ps += __shfl_xor(ps, 32);
    l_acc += ps;
    // ---- P^T -> LDS in A-layout rows: P[qrow=l15][t=tt*16+quad*4+r] ----
#pragma unroll
    for (int tt = 0; tt < 4; tt++) {
      half4 pk;
      pk[0] = (f16)sc[tt][0]; pk[1] = (f16)sc[tt][1];
      pk[2] = (f16)sc[tt][2]; pk[3] = (f16)sc[tt][3];
      *(half4*)&p_lds[w][l15 * PSTR + tt * 16 + quad * 4] = pk;
    }
    // ---- O += P V ----
#pragma unroll
    for (int ks = 0; ks < 2; ks++) {
      half8 pf = *(const half8*)&p_lds[w][l15 * PSTR + ks * 32 + quad * 8];
#pragma unroll
      for (int nt = 0; nt < 4; nt++)
        o[nt] = __builtin_amdgcn_mfma_f32_16x16x32_f16(pf, ks ? vf1[nt] : vf0[nt], o[nt], 0, 0, 0);
    }
    __syncthreads();  // K/V fragment reads done; next iter may overwrite
  }

  // l for qrow = quad*4+r lives in lane with l15 = quad*4+r
  float linv[4];
#pragma unroll
  for (int r = 0; r < 4; r++) linv[r] = 1.0f / __shfl(l_acc, quad * 4 + r);
#pragma unroll
  for (int nt = 0; nt < 4; nt++) {
#pragma unroll
    for (int r = 0; r < 4; r++) {
      int s = qrow0 + quad * 4 + r;
      out[((size_t)b * SEQ + s) * RES + h * HD + nt * 16 + l15] = o[nt][r] * linv[r];
    }
  }
}

extern "C" void kernel_launch(void* const* d_in, const int* in_sizes, int n_in,
                              void* d_out, int out_size, void* d_ws, size_t ws_size,
                              hipStream_t stream) {
  (void)in_sizes; (void)n_in; (void)out_size; (void)ws_size;
  const float* x  = (const float*)d_in[0];
  const float* Wq = (const float*)d_in[1];
  const float* Wk = (const float*)d_in[2];
  const float* Wv = (const float*)d_in[3];
  float* out = (float*)d_out;

  // workspace layout (fp16): xh 8MB | Wt 6MB | Qh 8MB | Kh 8MB | Vt 8MB = 38MB
  f16* xh = (f16*)d_ws;
  f16* Wt = xh + (size_t)M_ROWS * RES;
  f16* Qh = Wt + (size_t)3 * RES * RES;
  f16* Kh = Qh + (size_t)BATCH * NH * SEQ * HD;
  f16* Vt = Kh + (size_t)BATCH * NH * SEQ * HD;

  xconv_kernel<<<M_ROWS * RES / (256 * 8), 256, 0, stream>>>(x, xh);
  wtrans_kernel<<<dim3(32, 32, 3), dim3(32, 32), 0, stream>>>(Wq, Wk, Wv, Wt);
  proj_gemm_kernel<<<dim3(M_ROWS / 128, RES / 128, 3), 256, 0, stream>>>(xh, Wt, Qh, Kh, Vt);
  flash_kernel<<<1024, 256, 0, stream>>>(Qh, Kh, Vt, out);
}